// Round 6
// baseline (5100.473 us; speedup 1.0000x reference)
//
#include <hip/hip_runtime.h>
#include <hip/hip_bf16.h>

// B=64, S=512, I=256, H=512 LSTM forward.
// R11: barrier-free step. R10's counters + chain arithmetic showed the step
// time (~6700cy) is ~3x the serial-chain model (~2100cy): the gap is group-
// wide coupling -- two __syncthreads per step plus a max-over-64-producer-
// waves wait, re-synchronizing every wave to the slowest one every step.
// This round removes ALL intra-WG coupling from the loop:
//  (1) gate-local column remap: wave w, lane l16 owns gates {0,2}/{1,3} of
//      unit w*8+(l16&7); lane pair l16^8 exchanges via 4 __shfl_xor so the
//      eltwise runs fully in-register (no gate[] LDS round trip, no SYNC#2).
//  (2) h transport is a plain bf16 array [2][16][512]; the consumer A-frag
//      is 16 contiguous bytes = two agent-scope u64 loads straight into
//      MFMA fragments (no hL scatter, no SYNC#1, no LDS A-reads).
//  (3) per-producer-WAVE flag protocol: publish h (2 plain bf16 stores in
//      fast/XCD-pure mode; agent stores otherwise) -> vmcnt(0) -> one agent
//      flag store flags[w16*4+wave]=t+1. Consumer: lane L polls flags[L]
//      (pre-issued at tail), ONE __all(f>=t) check. Ring-2 safe: flag>=t
//      from wave X implies X finished READING h(t-2) (reads precede its
//      publish in program order), so overwriting parity t&1 is safe; the
//      >= check avoids run-ahead deadlock; wave spread is bounded <1 step.
// The loop has zero barriers and zero LDS traffic. Placement machinery
// (per-XCD claim + arrival barrier + verified counts) identical to R8-R10.

#define BB 64
#define SS 512
#define II 256
#define HH 512
#define G4 2048
#define NGRP 4     // batch groups
#define GB 16      // batches per group
#define NWPG 16    // WGs per group
#define NCOL 128   // gate cols per WG = 4 gates x 32 units
#define NU 32      // hidden units per WG

typedef __attribute__((ext_vector_type(8))) short bf16x8;
typedef __attribute__((ext_vector_type(4))) float f32x4;
typedef unsigned long long u64t;

__device__ __forceinline__ u64t ld_llc_u64(const u64t* p) {
  return __hip_atomic_load((u64t*)p, __ATOMIC_RELAXED,
                           __HIP_MEMORY_SCOPE_AGENT);
}
__device__ __forceinline__ unsigned ld_llc_u32(const unsigned* p) {
  return __hip_atomic_load((unsigned*)p, __ATOMIC_RELAXED,
                           __HIP_MEMORY_SCOPE_AGENT);
}
__device__ __forceinline__ void st_llc_u32(unsigned* p, unsigned v) {
  __hip_atomic_store(p, v, __ATOMIC_RELAXED, __HIP_MEMORY_SCOPE_AGENT);
}
__device__ __forceinline__ void st_llc_u16(unsigned short* p,
                                           unsigned short v) {
  __hip_atomic_store(p, v, __ATOMIC_RELAXED, __HIP_MEMORY_SCOPE_AGENT);
}

// x [b][t][i] fp32 -> xb [t][b][i] bf16
__global__ void convert_x_kernel(const float* __restrict__ x,
                                 __hip_bfloat16* __restrict__ xb) {
  int blk = blockIdx.x;          // b*SS + t
  int b = blk >> 9;
  int t = blk & (SS - 1);
  int i = threadIdx.x;
  xb[((size_t)t * BB + b) * II + i] = __float2bfloat16(x[(size_t)blk * II + i]);
}

// W [256][2048] fp32 -> Wt [2048][256] bf16 (row = gate col, for B-frags)
__global__ void transpose_w_kernel(const float* __restrict__ W,
                                   __hip_bfloat16* __restrict__ Wt) {
  __shared__ __hip_bfloat16 tile[64][64 + 8];
  int kb = blockIdx.x & 3;       // 4 k-blocks
  int nb = blockIdx.x >> 2;      // 32 n-blocks
  int k0 = kb * 64, nb0 = nb * 64;
#pragma unroll
  for (int p = 0; p < 16; ++p) {
    int r = p * 4 + (threadIdx.x >> 6);
    int c = threadIdx.x & 63;
    tile[r][c] = __float2bfloat16(W[(size_t)(k0 + r) * G4 + nb0 + c]);
  }
  __syncthreads();
#pragma unroll
  for (int p = 0; p < 16; ++p) {
    int n = p * 4 + (threadIdx.x >> 6);
    int k = threadIdx.x & 63;
    Wt[(size_t)(nb0 + n) * II + k0 + k] = tile[k][n];
  }
}

__global__ __launch_bounds__(256, 1)
void lstm_step(const float* __restrict__ U,
               const float* __restrict__ bias,
               const __hip_bfloat16* __restrict__ xb,
               const __hip_bfloat16* __restrict__ Wt,
               __hip_bfloat16* __restrict__ hbuf,  // [NGRP][2][GB][HH] bf16
               unsigned* __restrict__ flags,       // [NGRP][64] u32
               unsigned* cnt,  // 16 u32 in out-tail (aliases out: NO restrict)
               float* out) {
  // LDS: Ut 133.1K (staging; keeps 1 WG/CU) + bia 0.5K
  __shared__ alignas(16) __hip_bfloat16 Ut[NCOL][HH + 8];
  __shared__ float bia[NCOL];
  __shared__ int sh_grp, sh_w16, sh_fast;

  const int tid = threadIdx.x;

  // ---- claim + verified placement (identical to R8-R10, proven) ----
  if (tid == 0) {
    unsigned xcc;
    asm volatile("s_getreg_b32 %0, hwreg(HW_REG_XCC_ID)" : "=s"(xcc));
    xcc &= 7u;
    unsigned my = __hip_atomic_fetch_add(&cnt[xcc], 1u, __ATOMIC_RELAXED,
                                         __HIP_MEMORY_SCOPE_AGENT);
    __hip_atomic_fetch_add(&cnt[15], 1u, __ATOMIC_RELEASE,
                           __HIP_MEMORY_SCOPE_AGENT);
    while (__hip_atomic_load(&cnt[15], __ATOMIC_ACQUIRE,
                             __HIP_MEMORY_SCOPE_AGENT) < 256u) {}
    unsigned c0 = __hip_atomic_load(&cnt[0], __ATOMIC_RELAXED,
                                    __HIP_MEMORY_SCOPE_AGENT);
    unsigned c1 = __hip_atomic_load(&cnt[1], __ATOMIC_RELAXED,
                                    __HIP_MEMORY_SCOPE_AGENT);
    unsigned c2 = __hip_atomic_load(&cnt[2], __ATOMIC_RELAXED,
                                    __HIP_MEMORY_SCOPE_AGENT);
    unsigned c3 = __hip_atomic_load(&cnt[3], __ATOMIC_RELAXED,
                                    __HIP_MEMORY_SCOPE_AGENT);
    int fast = (c0 >= NWPG && c1 >= NWPG && c2 >= NWPG && c3 >= NWPG);
    int grp = -1, w16 = 0;
    if (fast) {
      if (xcc < NGRP && my < NWPG) { grp = (int)xcc; w16 = (int)my; }
    } else {
      unsigned sp = __hip_atomic_fetch_add(&cnt[9], 1u, __ATOMIC_RELAXED,
                                           __HIP_MEMORY_SCOPE_AGENT);
      if (sp < NGRP * NWPG) { grp = (int)(sp >> 4); w16 = (int)(sp & 15); }
    }
    sh_grp = grp; sh_w16 = w16; sh_fast = fast;
  }
  __syncthreads();
  const int grp = sh_grp;
  const int w16 = sh_w16;
  const bool fast = (bool)sh_fast;
  if (grp < 0) return;             // uniform exit, CU freed
  const int n0 = w16 * NU;         // hidden-unit offset of this WG's slice

  // ---- one-time: stage U column-slice (transposed, bf16) + bias ----
  // local col c: gate = c>>5, unit = c&31  <->  global col (c>>5)*512+n0+(c&31)
  for (int i = tid; i < NCOL * HH; i += 256) {
    int c = i & (NCOL - 1);
    int k = i >> 7;
    int g = c >> 5, j = c & 31;
    Ut[c][k] = __float2bfloat16(U[(size_t)k * G4 + g * HH + n0 + j]);
  }
  if (tid < NCOL) {
    int g = tid >> 5, j = tid & 31;
    bia[tid] = bias[g * HH + n0 + j];
  }
  __syncthreads();

  const int lane = tid & 63;
  const int wave = tid >> 6;
  const int l16 = lane & 15;
  const int quad = lane >> 4;
  const bool lo = (l16 < 8);

  // gate-local column remap: this lane's unit and its two gate-cols
  const int uloc = wave * 8 + (l16 & 7);        // local unit 0..31
  const int c0i = (lo ? 0 : 2) * 32 + uloc;     // gate i (lo) / g (hi)
  const int c1i = c0i + 32;                     // gate f (lo) / o (hi)

  // ---- one-time: hoist step-invariant B-operands into VGPRs ----
  bf16x8 uf0[16], uf1[16];
#pragma unroll
  for (int ks = 0; ks < 16; ++ks) {
    uf0[ks] = *(const bf16x8*)(&Ut[c0i][ks * 32 + quad * 8]);
    uf1[ks] = *(const bf16x8*)(&Ut[c1i][ks * 32 + quad * 8]);
  }
  const __hip_bfloat16* wrow0 =
      Wt + (size_t)((c0i >> 5) * HH + n0 + (c0i & 31)) * II;
  const __hip_bfloat16* wrow1 =
      Wt + (size_t)((c1i >> 5) * HH + n0 + (c1i & 31)) * II;
  bf16x8 wf0[8], wf1[8];
#pragma unroll
  for (int ks = 0; ks < 8; ++ks) {
    wf0[ks] = *(const bf16x8*)(wrow0 + ks * 32 + quad * 8);
    wf1[ks] = *(const bf16x8*)(wrow1 + ks * 32 + quad * 8);
  }
  const float b0 = bia[c0i];
  const float b1 = bia[c1i];

  // cell ownership: 2 cells = batches quad*4 + r0 + {0,1}, unit uloc
  const int r0 = lo ? 0 : 2;
  const int gu = n0 + uloc;        // global hidden unit
  float cs0 = 0.f, cs1 = 0.f;

  __hip_bfloat16* hb0 = hbuf + (size_t)grp * 2 * GB * HH;
  unsigned* flg = flags + grp * 64;
  const int fid = w16 * 4 + wave;  // this producer wave's flag

  // ---- prologue: prefetch xb(0) into regs ----
  bf16x8 xr[8];
  {
    const __hip_bfloat16* xrow = xb + ((size_t)0 * BB + grp * GB + l16) * II;
#pragma unroll
    for (int ks = 0; ks < 8; ++ks)
      xr[ks] = *(const bf16x8*)(xrow + ks * 32 + quad * 8);
  }
  unsigned fpoll = 0;              // t=0 wants >=0: trivially fresh

  for (int t = 0; t < SS; ++t) {
    const __hip_bfloat16* hbr = hb0 + (size_t)((t & 1) ^ 1) * GB * HH;
    __hip_bfloat16* hbw = hb0 + (size_t)(t & 1) * GB * HH;
    const unsigned want = (unsigned)t;

    // ---- ONE flag check: all 64 producer waves flagged >= t ----
    while (!__all((int)(fpoll >= want)))
      fpoll = ld_llc_u32(flg + lane);
    __builtin_amdgcn_sched_barrier(0);

    // ---- issue A-frag payload loads (agent scope: bypass stale L1, hit
    // the XCD L2 where producers' stores are dirty; R9-measured) ----
    const u64t* hq = (const u64t*)(hbr + (size_t)l16 * HH) + quad * 2;
    u64t pa[16], pb[16];
#pragma unroll
    for (int ks = 0; ks < 16; ++ks) {
      pa[ks] = ld_llc_u64(hq + ks * 8);
      pb[ks] = ld_llc_u64(hq + ks * 8 + 1);
    }

    // ---- x @ W from prefetched registers (covers payload RT) ----
    f32x4 acc0 = {b0, b0, b0, b0};
    f32x4 acc1 = {b1, b1, b1, b1};
#pragma unroll
    for (int ks = 0; ks < II / 32; ++ks) {
      acc0 = __builtin_amdgcn_mfma_f32_16x16x32_bf16(xr[ks], wf0[ks], acc0, 0, 0, 0);
      acc1 = __builtin_amdgcn_mfma_f32_16x16x32_bf16(xr[ks], wf1[ks], acc1, 0, 0, 0);
    }

    // ---- h @ U: A-frags assembled from the two u64 loads ----
#pragma unroll
    for (int ks = 0; ks < HH / 32; ++ks) {
      union { u64t a[2]; bf16x8 v; } u;
      u.a[0] = pa[ks];
      u.a[1] = pb[ks];
      acc0 = __builtin_amdgcn_mfma_f32_16x16x32_bf16(u.v, uf0[ks], acc0, 0, 0, 0);
      acc1 = __builtin_amdgcn_mfma_f32_16x16x32_bf16(u.v, uf1[ks], acc1, 0, 0, 0);
    }

    // ---- gate exchange (lane pair l16^8) + eltwise, fully in-register ----
    // lo lane holds (i,f) rows 0..3; hi lane holds (g,o) rows 0..3.
    // lo computes cells rows {0,1}, hi computes rows {2,3}.
    float hv[2];
#pragma unroll
    for (int s = 0; s < 2; ++s) {
      float send0 = lo ? acc0[2 + s] : acc0[s];
      float send1 = lo ? acc1[2 + s] : acc1[s];
      float rx0 = __shfl_xor(send0, 8, 64);
      float rx1 = __shfl_xor(send1, 8, 64);
      float xi = lo ? acc0[s] : rx0;       // i-gate
      float xf = lo ? acc1[s] : rx1;       // f
      float xg = lo ? rx0 : acc0[2 + s];   // g
      float xo = lo ? rx1 : acc1[2 + s];   // o
      float& cst = s ? cs1 : cs0;
      float it = 1.f / (1.f + __expf(-xi));
      float ft = 1.f / (1.f + __expf(-xf));
      float gx = fminf(fmaxf(xg, -15.f), 15.f);
      float eg = __expf(2.f * gx);
      float gt = (eg - 1.f) / (eg + 1.f);
      float ot = 1.f / (1.f + __expf(-xo));
      cst = ft * cst + it * gt;
      float cc = fminf(fmaxf(cst, -15.f), 15.f);
      float ec = __expf(2.f * cc);
      float th = (ec - 1.f) / (ec + 1.f);
      hv[s] = ot * th;
    }

    // ---- publish h (2 cells), ack, then flag ----
    union { __hip_bfloat16 h; unsigned short us; } p0, p1;
    p0.h = __float2bfloat16(hv[0]);
    p1.h = __float2bfloat16(hv[1]);
    __hip_bfloat16* w0 = hbw + (size_t)(quad * 4 + r0) * HH + gu;
    __hip_bfloat16* w1 = w0 + HH;
    if (fast) {
      // plain stores: write-through L1 -> dirty in local XCD L2
      *(unsigned short*)w0 = p0.us;
      *(unsigned short*)w1 = p1.us;
    } else {
      // impure placement: agent stores (write to coherence point)
      st_llc_u16((unsigned short*)w0, p0.us);
      st_llc_u16((unsigned short*)w1, p1.us);
    }
    asm volatile("s_waitcnt vmcnt(0)" ::: "memory");
    __builtin_amdgcn_sched_barrier(0);
    if (lane == 0) st_llc_u32(flg + fid, (unsigned)(t + 1));

    // ---- pre-issue next step's flag polls ----
    if (t + 1 < SS) fpoll = ld_llc_u32(flg + lane);
    __builtin_amdgcn_sched_barrier(0);

    // ---- xr prefetch (t+1): lands during next flag wait / payload RT ----
    if (t + 1 < SS) {
      const __hip_bfloat16* xrow =
          xb + ((size_t)(t + 1) * BB + grp * GB + l16) * II;
#pragma unroll
      for (int ks = 0; ks < 8; ++ks)
        xr[ks] = *(const bf16x8*)(xrow + ks * 32 + quad * 8);
    }

    // ---- outputs (off the critical chain) ----
    int bg0 = grp * GB + quad * 4 + r0;
    out[((size_t)bg0 * SS + t) * HH + gu] = hv[0];
    out[((size_t)(bg0 + 1) * SS + t) * HH + gu] = hv[1];
    if (t == SS - 1) {
      size_t base = (size_t)BB * SS * HH;
      out[base + (size_t)bg0 * HH + gu] = hv[0];                    // h_f
      out[base + (size_t)(bg0 + 1) * HH + gu] = hv[1];
      out[base + (size_t)BB * HH + (size_t)bg0 * HH + gu] = cs0;    // c_f
      out[base + (size_t)BB * HH + (size_t)(bg0 + 1) * HH + gu] = cs1;
    }
  }
}

extern "C" void kernel_launch(void* const* d_in, const int* in_sizes, int n_in,
                              void* d_out, int out_size, void* d_ws, size_t ws_size,
                              hipStream_t stream) {
  const float* x = (const float*)d_in[0];     // [64,512,256]
  const float* W = (const float*)d_in[1];     // [256,2048]
  const float* U = (const float*)d_in[2];     // [512,2048]
  const float* bias = (const float*)d_in[3];  // [2048]
  float* out = (float*)d_out;

  // ws layout: comm region occupies the same [0,256K) as all passing rounds.
  char* ws = (char*)d_ws;
  __hip_bfloat16* hbuf = (__hip_bfloat16*)ws;               // 128 KB
  unsigned* flags = (unsigned*)(ws + 128 * 1024);           // 1 KB
  __hip_bfloat16* Wt = (__hip_bfloat16*)(ws + 256 * 1024);  // 1 MB
  __hip_bfloat16* xb =
      (__hip_bfloat16*)(ws + 256 * 1024 + (size_t)G4 * II * 2);  // 16 MB

  // claim counters: last 64B of out (c_f tail; rewritten at t=SS-1 only,
  // long after all claims complete behind the arrival barrier).
  unsigned* cnt = (unsigned*)((char*)d_out + out_size - 64);

  // zero hbuf (h(-1)=0) + flags (epoch 0) + counters
  hipMemsetAsync(d_ws, 0, 256 * 1024, stream);
  hipMemsetAsync(cnt, 0, 64, stream);
  convert_x_kernel<<<BB * SS, II, 0, stream>>>(x, xb);
  transpose_w_kernel<<<128, 256, 0, stream>>>(W, Wt);
  // 256 WGs: LDS forces 1 WG/CU -> full chip; 64 claim work, rest exit.
  lstm_step<<<256, 256, 0, stream>>>(U, bias, xb, Wt, hbuf, flags, cnt, out);
}